// Round 1
// baseline (262.350 us; speedup 1.0000x reference)
//
#include <hip/hip_runtime.h>
#include <cstdint>

#define N_IMG 32
#define C_IN 128
#define H_IN 56
#define W_IN 56
#define K_OUT 256
#define HW (H_IN * W_IN)            // 3136
#define M_TOTAL (N_IMG * HW)        // 100352
#define XP_H 58
#define XP_W 58
#define XP_PLANE (XP_H * XP_W)      // 3364
#define XP_ELEMS (N_IMG * XP_PLANE * C_IN)   // 13,778,944 bf16
#define WT_ELEMS (9 * K_OUT * C_IN)          // 294,912 bf16

typedef __bf16 bf16x8 __attribute__((ext_vector_type(8)));
typedef float f32x4 __attribute__((ext_vector_type(4)));

// Static device scratch (no dependence on ws_size). Rewritten fully every call.
__device__ __align__(16) unsigned short g_xp[XP_ELEMS];  // padded NHWC bf16 input
__device__ __align__(16) unsigned short g_wt[WT_ELEMS];  // wt[rs][k][c] bf16 weights

static __device__ __forceinline__ unsigned short f2bf(float f) {
    unsigned int u = __builtin_bit_cast(unsigned int, f);
    u += 0x7fffu + ((u >> 16) & 1u);   // RNE
    return (unsigned short)(u >> 16);
}

// ---------------- prep kernel 1: zero padded input ----------------
__global__ __launch_bounds__(256) void zero_xp() {
    uint4* p = (uint4*)g_xp;
    int i = blockIdx.x * 256 + threadIdx.x;   // grid covers exactly XP_ELEMS*2/16
    p[i] = uint4{0u, 0u, 0u, 0u};
}

// ---------------- prep kernel 2: NCHW fp32 -> padded NHWC bf16 ----------------
// one block per (h, n); LDS transpose so both global read and write are coalesced
__global__ __launch_bounds__(256) void xpose_x(const float* __restrict__ x) {
    __shared__ float tile[C_IN * W_IN];   // [c][w], 28,672 B
    const int h = blockIdx.x;
    const int n = blockIdx.y;
    const int tid = threadIdx.x;
#pragma unroll
    for (int i = 0; i < 28; i++) {        // 28*256 = 7168 = 128*56
        int e = i * 256 + tid;
        int c = e / 56;
        int w = e - c * 56;
        tile[c * W_IN + w] = x[((n * C_IN + c) * H_IN + h) * W_IN + w];
    }
    __syncthreads();
    unsigned int* outp = (unsigned int*)g_xp;
#pragma unroll
    for (int i = 0; i < 14; i++) {        // 14*256 = 3584 = 56*64 (pairs of c)
        int u = i * 256 + tid;
        int w = u >> 6;                   // 0..55
        int cp = u & 63;                  // c pair
        float a = tile[(2 * cp) * W_IN + w];
        float b = tile[(2 * cp + 1) * W_IN + w];
        unsigned int pk = (unsigned int)f2bf(a) | ((unsigned int)f2bf(b) << 16);
        int idx = ((n * XP_H + h + 1) * XP_W + (w + 1)) * C_IN + 2 * cp;  // even
        outp[idx >> 1] = pk;
    }
}

// ---------------- prep kernel 3: OIHW fp32 -> wt[rs][k][c] bf16 ----------------
__global__ __launch_bounds__(256) void xpose_w(const float* __restrict__ w) {
    int e = blockIdx.x * 256 + threadIdx.x;   // grid covers exactly WT_ELEMS
    int rr = e >> 15;                          // / (256*128)
    int rem = e & 32767;
    int k = rem >> 7;
    int c = rem & 127;
    g_wt[e] = f2bf(w[(k * C_IN + c) * 9 + rr]);
}

// ---------------- main: implicit-GEMM bf16 MFMA ----------------
// block tile 128(M pixels) x 128(N out-ch), BK=32, 4 waves (2x2), 4x4 mfma accs/wave
__global__ __launch_bounds__(256, 2) void conv_main(float* __restrict__ out) {
    __shared__ __align__(16) unsigned short As[128 * 32];
    __shared__ __align__(16) unsigned short Bs[128 * 32];
    const unsigned short* xp = g_xp;
    const unsigned short* wt = g_wt;

    const int tid = threadIdx.x;
    const int m0 = blockIdx.x * 128;
    const int k0 = blockIdx.y * 128;
    const int wave = tid >> 6, lane = tid & 63;
    const int wm = (wave & 1) * 64;      // wave m-offset in block
    const int wn = (wave >> 1) * 64;     // wave n-offset in block
    const int lr = lane & 15;            // row-in-16 / col-in-16
    const int lq = lane >> 4;            // quad

    // staging precompute: 512 units of 16B; unit u -> (row = u>>2, cgroup = u&3)
    int a_base[2], sm_off[2], b_base[2];
#pragma unroll
    for (int j = 0; j < 2; j++) {
        int u = j * 256 + tid;
        int ml = u >> 2;                 // 0..127
        int cg = u & 3;
        int p = m0 + ml;
        int n = p / HW;
        int rem = p - n * HW;
        int h = rem / W_IN;
        int w = rem - h * W_IN;
        a_base[j] = ((n * XP_H + h) * XP_W + w) * C_IN + cg * 8;
        sm_off[j] = ml * 32 + cg * 8;
        b_base[j] = (k0 + ml) * C_IN + cg * 8;
    }

    f32x4 acc[4][4];
#pragma unroll
    for (int mi = 0; mi < 4; mi++)
#pragma unroll
        for (int ni = 0; ni < 4; ni++)
            acc[mi][ni] = f32x4{0.f, 0.f, 0.f, 0.f};

#pragma unroll
    for (int rr = 0; rr < 9; rr++) {
        const int rs_off = ((rr / 3) * XP_W + (rr % 3)) * C_IN;
        const int wt_off = rr * (K_OUT * C_IN);
#pragma unroll
        for (int c0 = 0; c0 < 128; c0 += 32) {
#pragma unroll
            for (int j = 0; j < 2; j++) {
                bf16x8 av = *(const bf16x8*)(xp + a_base[j] + rs_off + c0);
                bf16x8 bv = *(const bf16x8*)(wt + wt_off + b_base[j] + c0);
                *(bf16x8*)(As + sm_off[j]) = av;
                *(bf16x8*)(Bs + sm_off[j]) = bv;
            }
            __syncthreads();
            bf16x8 af[4], bfr[4];
#pragma unroll
            for (int i = 0; i < 4; i++)
                af[i] = *(const bf16x8*)(As + (wm + i * 16 + lr) * 32 + lq * 8);
#pragma unroll
            for (int i = 0; i < 4; i++)
                bfr[i] = *(const bf16x8*)(Bs + (wn + i * 16 + lr) * 32 + lq * 8);
#pragma unroll
            for (int mi = 0; mi < 4; mi++)
#pragma unroll
                for (int ni = 0; ni < 4; ni++)
                    acc[mi][ni] = __builtin_amdgcn_mfma_f32_16x16x32_bf16(
                        af[mi], bfr[ni], acc[mi][ni], 0, 0, 0);
            __syncthreads();
        }
    }

    // epilogue: lane's float4 = 4 consecutive pixels at fixed out-channel k
#pragma unroll
    for (int mi = 0; mi < 4; mi++) {
        int p = m0 + wm + mi * 16 + lq * 4;   // multiple of 4; 3136%4==0 -> same n
        int n = p / HW;
        int off = p - n * HW;
#pragma unroll
        for (int ni = 0; ni < 4; ni++) {
            int k = k0 + wn + ni * 16 + lr;
            *(f32x4*)(out + (n * K_OUT + k) * HW + off) = acc[mi][ni];
        }
    }
}

extern "C" void kernel_launch(void* const* d_in, const int* in_sizes, int n_in,
                              void* d_out, int out_size, void* d_ws, size_t ws_size,
                              hipStream_t stream) {
    const float* x = (const float*)d_in[0];
    const float* w = (const float*)d_in[1];
    float* out = (float*)d_out;

    hipLaunchKernelGGL(zero_xp, dim3((XP_ELEMS * 2) / 16 / 256), dim3(256), 0, stream);
    hipLaunchKernelGGL(xpose_x, dim3(H_IN, N_IMG), dim3(256), 0, stream, x);
    hipLaunchKernelGGL(xpose_w, dim3(WT_ELEMS / 256), dim3(256), 0, stream, w);
    hipLaunchKernelGGL(conv_main, dim3(M_TOTAL / 128, K_OUT / 128), dim3(256), 0, stream, out);
}

// Round 2
// 257.844 us; speedup vs baseline: 1.0175x; 1.0175x over previous
//
#include <hip/hip_runtime.h>
#include <cstdint>

#define N_IMG 32
#define C_IN 128
#define H_IN 56
#define W_IN 56
#define K_OUT 256
#define HW (H_IN * W_IN)            // 3136
#define M_TOTAL (N_IMG * HW)        // 100352
#define XP_H 58
#define XP_W 58
#define XP_PLANE (XP_H * XP_W)      // 3364
#define XP_ELEMS (N_IMG * XP_PLANE * C_IN)   // 13,778,944 bf16
#define WT_ELEMS (9 * K_OUT * C_IN)          // 294,912 bf16

typedef __bf16 bf16x8 __attribute__((ext_vector_type(8)));
typedef float f32x4 __attribute__((ext_vector_type(4)));

// Static device scratch (no dependence on ws_size). Rewritten fully every call.
__device__ __align__(16) unsigned short g_xp[XP_ELEMS];  // padded NHWC bf16 input
__device__ __align__(16) unsigned short g_wt[WT_ELEMS];  // wt[rs][k][c] bf16 weights

static __device__ __forceinline__ unsigned short f2bf(float f) {
    unsigned int u = __builtin_bit_cast(unsigned int, f);
    u += 0x7fffu + ((u >> 16) & 1u);   // RNE
    return (unsigned short)(u >> 16);
}

// async global->LDS, 16 bytes per lane; LDS dest = wave-uniform base + lane*16
static __device__ __forceinline__ void async_copy16(const unsigned short* g, unsigned short* l) {
    auto gp = (const __attribute__((address_space(1))) unsigned int*)g;
    auto lp = (__attribute__((address_space(3))) unsigned int*)l;
    __builtin_amdgcn_global_load_lds(gp, lp, 16, 0, 0);
}

// ---------------- prep kernel 1: zero padded input ----------------
__global__ __launch_bounds__(256) void zero_xp() {
    uint4* p = (uint4*)g_xp;
    int i = blockIdx.x * 256 + threadIdx.x;   // grid covers exactly XP_ELEMS*2/16
    p[i] = uint4{0u, 0u, 0u, 0u};
}

// ---------------- prep kernel 2: NCHW fp32 -> padded NHWC bf16 ----------------
// one block per (h, n); LDS transpose so both global read and write are coalesced.
// tile stride 57 (not 56): read lane-stride 114 words -> 16 banks (4-way, ~free)
// instead of 112 words -> 2 banks (32-way, ~11x).
__global__ __launch_bounds__(256) void xpose_x(const float* __restrict__ x) {
    __shared__ float tile[C_IN * 57];     // [c][w] padded, 29,184 B
    const int h = blockIdx.x;
    const int n = blockIdx.y;
    const int tid = threadIdx.x;
#pragma unroll
    for (int i = 0; i < 28; i++) {        // 28*256 = 7168 = 128*56
        int e = i * 256 + tid;
        int c = e / 56;
        int w = e - c * 56;
        tile[c * 57 + w] = x[((n * C_IN + c) * H_IN + h) * W_IN + w];
    }
    __syncthreads();
    unsigned int* outp = (unsigned int*)g_xp;
#pragma unroll
    for (int i = 0; i < 14; i++) {        // 14*256 = 3584 = 56*64 (pairs of c)
        int u = i * 256 + tid;
        int w = u >> 6;                   // 0..55
        int cp = u & 63;                  // c pair
        float a = tile[(2 * cp) * 57 + w];
        float b = tile[(2 * cp + 1) * 57 + w];
        unsigned int pk = (unsigned int)f2bf(a) | ((unsigned int)f2bf(b) << 16);
        int idx = ((n * XP_H + h + 1) * XP_W + (w + 1)) * C_IN + 2 * cp;  // even
        outp[idx >> 1] = pk;
    }
}

// ---------------- prep kernel 3: OIHW fp32 -> wt[rs][k][c] bf16 ----------------
__global__ __launch_bounds__(256) void xpose_w(const float* __restrict__ w) {
    int e = blockIdx.x * 256 + threadIdx.x;   // grid covers exactly WT_ELEMS
    int rr = e >> 15;                          // / (256*128)
    int rem = e & 32767;
    int k = rem >> 7;
    int c = rem & 127;
    g_wt[e] = f2bf(w[(k * C_IN + c) * 9 + rr]);
}

// ---------------- main: implicit-GEMM bf16 MFMA ----------------
// block tile 128(M pixels) x 128(N out-ch), BK=32, 4 waves (2x2), 4x4 mfma accs/wave
// staging via global_load_lds width=16 (m97 pattern)
__global__ __launch_bounds__(256, 4) void conv_main(float* __restrict__ out) {
    __shared__ __align__(16) unsigned short As[128 * 32];
    __shared__ __align__(16) unsigned short Bs[128 * 32];
    const unsigned short* xp = g_xp;
    const unsigned short* wt = g_wt;

    const int tid = threadIdx.x;
    const int m0 = blockIdx.x * 128;
    const int k0 = blockIdx.y * 128;
    const int wave = tid >> 6, lane = tid & 63;
    const int wm = (wave & 1) * 64;      // wave m-offset in block
    const int wn = (wave >> 1) * 64;     // wave n-offset in block
    const int lr = lane & 15;            // row-in-16 / col-in-16
    const int lq = lane >> 4;            // quad

    // staging: 512 units of 16B per matrix; unit u = j*256+tid -> LDS byte u*16
    // (wave-uniform base + lane*16 -- required by global_load_lds)
    int a_base[2], b_base[2];
    unsigned short* a_lds[2];
    unsigned short* b_lds[2];
#pragma unroll
    for (int j = 0; j < 2; j++) {
        int u = j * 256 + tid;
        int ml = u >> 2;                 // 0..127
        int cg = u & 3;
        int p = m0 + ml;
        int n = p / HW;
        int rem = p - n * HW;
        int h = rem / W_IN;
        int w = rem - h * W_IN;
        a_base[j] = ((n * XP_H + h) * XP_W + w) * C_IN + cg * 8;
        b_base[j] = (k0 + ml) * C_IN + cg * 8;
        a_lds[j] = As + (j * 256 + wave * 64) * 8;   // wave-uniform
        b_lds[j] = Bs + (j * 256 + wave * 64) * 8;
    }

    f32x4 acc[4][4];
#pragma unroll
    for (int mi = 0; mi < 4; mi++)
#pragma unroll
        for (int ni = 0; ni < 4; ni++)
            acc[mi][ni] = f32x4{0.f, 0.f, 0.f, 0.f};

#pragma unroll
    for (int rr = 0; rr < 9; rr++) {
        const int rs_off = ((rr / 3) * XP_W + (rr % 3)) * C_IN;
        const int wt_off = rr * (K_OUT * C_IN);
#pragma unroll
        for (int c0 = 0; c0 < 128; c0 += 32) {
            async_copy16(xp + a_base[0] + rs_off + c0, a_lds[0]);
            async_copy16(xp + a_base[1] + rs_off + c0, a_lds[1]);
            async_copy16(wt + wt_off + b_base[0] + c0, b_lds[0]);
            async_copy16(wt + wt_off + b_base[1] + c0, b_lds[1]);
            __syncthreads();
            bf16x8 af[4], bfr[4];
#pragma unroll
            for (int i = 0; i < 4; i++)
                af[i] = *(const bf16x8*)(As + (wm + i * 16 + lr) * 32 + lq * 8);
#pragma unroll
            for (int i = 0; i < 4; i++)
                bfr[i] = *(const bf16x8*)(Bs + (wn + i * 16 + lr) * 32 + lq * 8);
#pragma unroll
            for (int mi = 0; mi < 4; mi++)
#pragma unroll
                for (int ni = 0; ni < 4; ni++)
                    acc[mi][ni] = __builtin_amdgcn_mfma_f32_16x16x32_bf16(
                        af[mi], bfr[ni], acc[mi][ni], 0, 0, 0);
            __syncthreads();
        }
    }

    // epilogue: lane's float4 = 4 consecutive pixels at fixed out-channel k
#pragma unroll
    for (int mi = 0; mi < 4; mi++) {
        int p = m0 + wm + mi * 16 + lq * 4;   // multiple of 4; 3136%4==0 -> same n
        int n = p / HW;
        int off = p - n * HW;
#pragma unroll
        for (int ni = 0; ni < 4; ni++) {
            int k = k0 + wn + ni * 16 + lr;
            *(f32x4*)(out + (n * K_OUT + k) * HW + off) = acc[mi][ni];
        }
    }
}

extern "C" void kernel_launch(void* const* d_in, const int* in_sizes, int n_in,
                              void* d_out, int out_size, void* d_ws, size_t ws_size,
                              hipStream_t stream) {
    const float* x = (const float*)d_in[0];
    const float* w = (const float*)d_in[1];
    float* out = (float*)d_out;

    hipLaunchKernelGGL(zero_xp, dim3((XP_ELEMS * 2) / 16 / 256), dim3(256), 0, stream);
    hipLaunchKernelGGL(xpose_x, dim3(H_IN, N_IMG), dim3(256), 0, stream, x);
    hipLaunchKernelGGL(xpose_w, dim3(WT_ELEMS / 256), dim3(256), 0, stream, w);
    hipLaunchKernelGGL(conv_main, dim3(M_TOTAL / 128, K_OUT / 128), dim3(256), 0, stream, out);
}

// Round 3
// 255.965 us; speedup vs baseline: 1.0249x; 1.0073x over previous
//
#include <hip/hip_runtime.h>
#include <cstdint>

#define N_IMG 32
#define C_IN 128
#define H_IN 56
#define W_IN 56
#define K_OUT 256
#define HW (H_IN * W_IN)            // 3136
#define M_TOTAL (N_IMG * HW)        // 100352
#define XP_H 58
#define XP_W 58
#define XP_ELEMS (N_IMG * XP_H * XP_W * C_IN)   // 13,778,944 bf16
#define WT_ELEMS (9 * K_OUT * C_IN)             // 294,912 bf16
#define N_STAGE 36                  // 9 rs positions x 4 c-chunks of 32

typedef __bf16 bf16x8 __attribute__((ext_vector_type(8)));
typedef float f32x4 __attribute__((ext_vector_type(4)));

__device__ __align__(16) unsigned short g_xp[XP_ELEMS];  // padded NHWC bf16 input
__device__ __align__(16) unsigned short g_wt[WT_ELEMS];  // wt[rs][k][c] bf16 weights

static __device__ __forceinline__ unsigned short f2bf(float f) {
    unsigned int u = __builtin_bit_cast(unsigned int, f);
    u += 0x7fffu + ((u >> 16) & 1u);   // RNE
    return (unsigned short)(u >> 16);
}

// async global->LDS, 16 bytes per lane; LDS dest = wave-uniform base + lane*16
static __device__ __forceinline__ void async_copy16(const unsigned short* g, unsigned short* l) {
    auto gp = (const __attribute__((address_space(1))) unsigned int*)g;
    auto lp = (__attribute__((address_space(3))) unsigned int*)l;
    __builtin_amdgcn_global_load_lds(gp, lp, 16, 0, 0);
}

// ---------------- prep kernel 1: NCHW fp32 -> padded NHWC bf16 (+border zero) --
// one block per (h, n); LDS transpose so both global read and write are coalesced.
// tile stride 57: read lane-stride 114 words -> 16 banks (4-way, near-free).
__global__ __launch_bounds__(256) void xpose_x(const float* __restrict__ x) {
    __shared__ float tile[C_IN * 57];     // [c][w] padded
    const int h = blockIdx.x;
    const int n = blockIdx.y;
    const int tid = threadIdx.x;

    // zero w-borders (w=0, w=57) of this block's padded row h+1
    if (tid < 32) {
        int col = (tid >> 4) * (XP_W - 1);          // 0 or 57
        int q = tid & 15;                            // 16B unit within 128 shorts
        uint4* dst = (uint4*)(g_xp + ((size_t)(n * XP_H + h + 1) * XP_W + col) * C_IN) + q;
        *dst = uint4{0u, 0u, 0u, 0u};
    }
    // edge blocks zero the top/bottom padded rows
    if (h == 0 || h == H_IN - 1) {
        int hp = (h == 0) ? 0 : XP_H - 1;
        uint4* base = (uint4*)(g_xp + ((size_t)(n * XP_H + hp) * XP_W) * C_IN);
        for (int q = tid; q < (XP_W * C_IN) / 8; q += 256) base[q] = uint4{0u, 0u, 0u, 0u};
    }

#pragma unroll
    for (int i = 0; i < 28; i++) {        // 28*256 = 7168 = 128*56
        int e = i * 256 + tid;
        int c = e / 56;
        int w = e - c * 56;
        tile[c * 57 + w] = x[((n * C_IN + c) * H_IN + h) * W_IN + w];
    }
    __syncthreads();
    unsigned int* outp = (unsigned int*)g_xp;
#pragma unroll
    for (int i = 0; i < 14; i++) {        // 14*256 = 3584 = 56*64 (pairs of c)
        int u = i * 256 + tid;
        int w = u >> 6;                   // 0..55
        int cp = u & 63;                  // c pair
        float a = tile[(2 * cp) * 57 + w];
        float b = tile[(2 * cp + 1) * 57 + w];
        unsigned int pk = (unsigned int)f2bf(a) | ((unsigned int)f2bf(b) << 16);
        int idx = ((n * XP_H + h + 1) * XP_W + (w + 1)) * C_IN + 2 * cp;  // even
        outp[idx >> 1] = pk;
    }
}

// ---------------- prep kernel 2: OIHW fp32 -> wt[rs][k][c] bf16 ----------------
__global__ __launch_bounds__(256) void xpose_w(const float* __restrict__ w) {
    int e = blockIdx.x * 256 + threadIdx.x;   // grid covers exactly WT_ELEMS
    int rr = e >> 15;                          // / (256*128)
    int rem = e & 32767;
    int k = rem >> 7;
    int c = rem & 127;
    g_wt[e] = f2bf(w[(k * C_IN + c) * 9 + rr]);
}

// ---------------- main: implicit-GEMM bf16 MFMA, single-barrier dbuf pipeline --
// block tile 128(M pixels) x 128(N out-ch), BK=32, 4 waves (2x2), 4x4 accs/wave.
// Prefetch stage s+1 into alternate LDS buffer right after the barrier, before
// computing stage s -> one __syncthreads per stage, load latency overlaps MFMA.
__global__ __launch_bounds__(256, 4) void conv_main(float* __restrict__ out) {
    __shared__ __align__(16) unsigned short As[2][128 * 32];
    __shared__ __align__(16) unsigned short Bs[2][128 * 32];
    const unsigned short* xp = g_xp;
    const unsigned short* wt = g_wt;

    const int tid = threadIdx.x;
    const int m0 = blockIdx.x * 128;
    const int k0 = blockIdx.y * 128;
    const int wave = tid >> 6, lane = tid & 63;
    const int wm = (wave & 1) * 64;      // wave m-offset in block
    const int wn = (wave >> 1) * 64;     // wave n-offset in block
    const int lr = lane & 15;            // row-in-16 / col-in-16
    const int lq = lane >> 4;            // quad

    // staging: 512 units of 16B per matrix; unit u = j*256+tid -> LDS byte u*16
    int a_base[2], b_base[2], lds_off[2];
#pragma unroll
    for (int j = 0; j < 2; j++) {
        int u = j * 256 + tid;
        int ml = u >> 2;                 // 0..127
        int cg = u & 3;
        int p = m0 + ml;
        int n = p / HW;
        int rem = p - n * HW;
        int h = rem / W_IN;
        int w = rem - h * W_IN;
        a_base[j] = ((n * XP_H + h) * XP_W + w) * C_IN + cg * 8;
        b_base[j] = (k0 + ml) * C_IN + cg * 8;
        lds_off[j] = (j * 256 + wave * 64) * 8;   // wave-uniform base + lane*16B
    }

    // stage s: rs = s>>2 (0..8), c-chunk = (s&3)*32
    auto issue = [&](int s, int buf) {
        int rs = s >> 2;
        int c0 = (s & 3) << 5;
        int r = (rs * 11) >> 5;          // rs / 3 for rs < 10
        int sc = rs - r * 3;             // rs % 3
        int a_off = (r * XP_W + sc) * C_IN + c0;
        int b_off = rs * (K_OUT * C_IN) + c0;
#pragma unroll
        for (int j = 0; j < 2; j++) {
            async_copy16(xp + a_base[j] + a_off, &As[buf][0] + lds_off[j]);
            async_copy16(wt + b_base[j] + b_off, &Bs[buf][0] + lds_off[j]);
        }
    };

    f32x4 acc[4][4];
#pragma unroll
    for (int mi = 0; mi < 4; mi++)
#pragma unroll
        for (int ni = 0; ni < 4; ni++)
            acc[mi][ni] = f32x4{0.f, 0.f, 0.f, 0.f};

    issue(0, 0);
#pragma unroll 2
    for (int s = 0; s < N_STAGE; s++) {
        const int cb = s & 1;
        __syncthreads();                  // drains loads(s); LDS(s-1) reads done
        if (s + 1 < N_STAGE) issue(s + 1, cb ^ 1);   // overlap with compute below
        bf16x8 af[4], bfr[4];
#pragma unroll
        for (int i = 0; i < 4; i++)
            af[i] = *(const bf16x8*)(&As[cb][0] + (wm + i * 16 + lr) * 32 + lq * 8);
#pragma unroll
        for (int i = 0; i < 4; i++)
            bfr[i] = *(const bf16x8*)(&Bs[cb][0] + (wn + i * 16 + lr) * 32 + lq * 8);
#pragma unroll
        for (int mi = 0; mi < 4; mi++)
#pragma unroll
            for (int ni = 0; ni < 4; ni++)
                acc[mi][ni] = __builtin_amdgcn_mfma_f32_16x16x32_bf16(
                    af[mi], bfr[ni], acc[mi][ni], 0, 0, 0);
    }

    // epilogue: lane's float4 = 4 consecutive pixels at fixed out-channel k
#pragma unroll
    for (int mi = 0; mi < 4; mi++) {
        int p = m0 + wm + mi * 16 + lq * 4;   // multiple of 4; 3136%4==0 -> same n
        int n = p / HW;
        int off = p - n * HW;
#pragma unroll
        for (int ni = 0; ni < 4; ni++) {
            int k = k0 + wn + ni * 16 + lr;
            *(f32x4*)(out + (n * K_OUT + k) * HW + off) = acc[mi][ni];
        }
    }
}

extern "C" void kernel_launch(void* const* d_in, const int* in_sizes, int n_in,
                              void* d_out, int out_size, void* d_ws, size_t ws_size,
                              hipStream_t stream) {
    const float* x = (const float*)d_in[0];
    const float* w = (const float*)d_in[1];
    float* out = (float*)d_out;

    hipLaunchKernelGGL(xpose_x, dim3(H_IN, N_IMG), dim3(256), 0, stream, x);
    hipLaunchKernelGGL(xpose_w, dim3(WT_ELEMS / 256), dim3(256), 0, stream, w);
    hipLaunchKernelGGL(conv_main, dim3(M_TOTAL / 128, K_OUT / 128), dim3(256), 0, stream, out);
}